// Round 2
// baseline (6239.053 us; speedup 1.0000x reference)
//
#include <hip/hip_runtime.h>
#include <hip/hip_bf16.h>

typedef __hip_bfloat16 bf16;

__device__ __forceinline__ float b2f(bf16 v) { return __bfloat162float(v); }
__device__ __forceinline__ float lrelu(float v) { return v >= 0.f ? v : 0.2f * v; }
// Uniform-branch input load: isbf ? bf16[i] : fp32[i]
__device__ __forceinline__ float ldin(const void* p, size_t i, int isbf) {
    if (isbf) return b2f(((const bf16*)p)[i]);
    return ((const float*)p)[i];
}

// ---------------------------------------------------------------------------
// Probe: decide whether inputs are bf16 or fp32 by inspecting x's halfwords.
// bf16 N(0,1) data: every halfword exponent in [100,140]. fp32 data: low
// halfwords are uniform random bits -> implausible exponents abound.
// ---------------------------------------------------------------------------
__global__ __launch_bounds__(256)
void probe_kernel(const void* __restrict__ x, int* __restrict__ flag) {
    const int tid = threadIdx.x;
    __shared__ int bad;
    if (tid == 0) bad = 0;
    __syncthreads();
    const unsigned short* h = (const unsigned short*)x;
    for (int k = tid; k < 512; k += 256) {
        const unsigned e = (h[k] >> 7) & 0xFFu;
        if (e < 100u || e > 140u) atomicAdd(&bad, 1);
    }
    __syncthreads();
    if (tid == 0) flag[0] = (bad == 0) ? 1 : 0;
}

// ---------------------------------------------------------------------------
// Kernel A: per-batch effective weights (fp32 out).
//   w1eff[b][i][t][o] = w1[o][i][t]*style1[i]*d1[o];  scwf[i][o] = sc_w[o][i]
// ---------------------------------------------------------------------------
__global__ __launch_bounds__(256)
void weights_kernel(const void* __restrict__ s,
                    const void* __restrict__ a1w, const void* __restrict__ a1b,
                    const void* __restrict__ w1,
                    const void* __restrict__ a2w, const void* __restrict__ a2b,
                    const void* __restrict__ w2,
                    const void* __restrict__ scw_in,
                    float* __restrict__ w1eff, float* __restrict__ w2eff,
                    float* __restrict__ scwf, const int* __restrict__ flag) {
    const int isbf = flag[0];
    const int b = blockIdx.x;
    const int tid = threadIdx.x;
    __shared__ float sb[64];
    __shared__ float st1[64];
    __shared__ float st2[128];
    __shared__ float d1[128];
    __shared__ float d2[128];

    if (tid < 64) sb[tid] = ldin(s, b * 64 + tid, isbf);
    __syncthreads();

    if (tid < 64) {
        float a = ldin(a1b, tid, isbf) + 1.f;
        for (int j = 0; j < 64; ++j) a += sb[j] * ldin(a1w, tid * 64 + j, isbf);
        st1[tid] = a;
    }
    if (tid >= 128 && tid < 256) {
        const int i = tid - 128;
        float a = ldin(a2b, i, isbf) + 1.f;
        for (int j = 0; j < 64; ++j) a += sb[j] * ldin(a2w, i * 64 + j, isbf);
        st2[i] = a;
    }
    __syncthreads();

    if (tid < 128) {
        float acc = 0.f;
        for (int i = 0; i < 64; ++i) {
            const float st = st1[i];
            for (int t = 0; t < 9; ++t) {
                const float v = ldin(w1, (tid * 64 + i) * 9 + t, isbf) * st;
                acc += v * v;
            }
        }
        d1[tid] = rsqrtf(acc + 1e-8f);
    } else {
        const int o = tid - 128;
        float acc = 0.f;
        for (int i = 0; i < 128; ++i) {
            const float st = st2[i];
            for (int t = 0; t < 9; ++t) {
                const float v = ldin(w2, (o * 128 + i) * 9 + t, isbf) * st;
                acc += v * v;
            }
        }
        d2[o] = rsqrtf(acc + 1e-8f);
    }
    __syncthreads();

    for (int idx = tid; idx < 128 * 64 * 9; idx += 256) {
        const int o = idx / 576;
        const int r = idx - o * 576;
        const int i = r / 9;
        const int t = r - i * 9;
        w1eff[(((size_t)b * 64 + i) * 9 + t) * 128 + o] = ldin(w1, idx, isbf) * st1[i] * d1[o];
    }
    for (int idx = tid; idx < 128 * 128 * 9; idx += 256) {
        const int o = idx / 1152;
        const int r = idx - o * 1152;
        const int i = r / 9;
        const int t = r - i * 9;
        w2eff[(((size_t)b * 128 + i) * 9 + t) * 128 + o] = ldin(w2, idx, isbf) * st2[i] * d2[o];
    }
    if (b == 0) {
        for (int idx = tid; idx < 128 * 64; idx += 256) {
            const int o = idx / 64;
            const int i = idx - o * 64;
            scwf[i * 128 + o] = ldin(scw_in, idx, isbf);
        }
    }
}

// ---------------------------------------------------------------------------
// Kernel B: conv1.  h1 = lrelu( conv3x3(lrelu(x), w1eff[b]) + nw*noise )
// ---------------------------------------------------------------------------
__global__ __launch_bounds__(256)
void conv1_kernel(const void* __restrict__ x, const void* __restrict__ noise,
                  const void* __restrict__ noise_w,
                  const float* __restrict__ w1eff, bf16* __restrict__ h1,
                  const int* __restrict__ flag) {
    __shared__ float lds[32 * 324];  // 41472 B
    const int isbf = flag[0];
    const int bx = blockIdx.x, by = blockIdx.y, bz = blockIdx.z;
    const int b = bz >> 3;
    const int ocb = (bz & 7) * 16;
    const int tid = threadIdx.x;
    const int px = tid & 15, py = tid >> 4;
    const int gx = bx * 16 + px, gy = by * 16 + py;
    const int x0 = bx * 16 - 1, y0 = by * 16 - 1;

    float acc[16];
#pragma unroll
    for (int i = 0; i < 16; ++i) acc[i] = 0.f;

    for (int cc = 0; cc < 64; cc += 32) {
        if (isbf) {
            const bf16* xp = (const bf16*)x;
            for (int idx = tid; idx < 32 * 324; idx += 256) {
                const int ci = idx / 324;
                const int r = idx - ci * 324;
                const int iy = r / 18;
                const int ix = r - iy * 18;
                const int sy = y0 + iy, sx = x0 + ix;
                float v = 0.f;
                if ((unsigned)sy < 256u && (unsigned)sx < 256u)
                    v = lrelu(b2f(xp[(((size_t)b * 64 + cc + ci) << 16) + (sy << 8) + sx]));
                lds[idx] = v;
            }
        } else {
            const float* xp = (const float*)x;
            for (int idx = tid; idx < 32 * 324; idx += 256) {
                const int ci = idx / 324;
                const int r = idx - ci * 324;
                const int iy = r / 18;
                const int ix = r - iy * 18;
                const int sy = y0 + iy, sx = x0 + ix;
                float v = 0.f;
                if ((unsigned)sy < 256u && (unsigned)sx < 256u)
                    v = lrelu(xp[(((size_t)b * 64 + cc + ci) << 16) + (sy << 8) + sx]);
                lds[idx] = v;
            }
        }
        __syncthreads();

        for (int ci = 0; ci < 32; ++ci) {
            float vin[9];
            const float* lp = &lds[ci * 324 + py * 18 + px];
#pragma unroll
            for (int kh = 0; kh < 3; ++kh)
#pragma unroll
                for (int kw = 0; kw < 3; ++kw) vin[kh * 3 + kw] = lp[kh * 18 + kw];
            const float* wp = w1eff + (((size_t)b * 64 + (cc + ci)) * 9) * 128 + ocb;
#pragma unroll
            for (int t = 0; t < 9; ++t) {
#pragma unroll
                for (int oc = 0; oc < 16; ++oc)
                    acc[oc] = fmaf(vin[t], wp[t * 128 + oc], acc[oc]);
            }
        }
        __syncthreads();
    }

    const float nw = ldin(noise_w, 0, isbf);
    const float nv = nw * ldin(noise, ((size_t)b << 16) + (gy << 8) + gx, isbf);
#pragma unroll
    for (int oc = 0; oc < 16; ++oc) {
        const float v = lrelu(acc[oc] + nv);
        h1[(((size_t)b * 128 + ocb + oc) << 16) + (gy << 8) + gx] = __float2bfloat16(v);
    }
}

// ---------------------------------------------------------------------------
// Kernel C: conv2 + noise + 1x1 shortcut + final scale.
// ---------------------------------------------------------------------------
__global__ __launch_bounds__(256)
void conv2_kernel(const bf16* __restrict__ h1, const void* __restrict__ x,
                  const void* __restrict__ noise, const void* __restrict__ noise_w,
                  const float* __restrict__ w2eff, const float* __restrict__ scwf,
                  void* __restrict__ out, const int* __restrict__ flag) {
    __shared__ float lds[32 * 324];
    const int isbf = flag[0];
    const int bx = blockIdx.x, by = blockIdx.y, bz = blockIdx.z;
    const int b = bz >> 3;
    const int ocb = (bz & 7) * 16;
    const int tid = threadIdx.x;
    const int px = tid & 15, py = tid >> 4;
    const int gx = bx * 16 + px, gy = by * 16 + py;
    const int x0 = bx * 16 - 1, y0 = by * 16 - 1;

    float acc[16];
#pragma unroll
    for (int i = 0; i < 16; ++i) acc[i] = 0.f;

    for (int cc = 0; cc < 128; cc += 32) {
        for (int idx = tid; idx < 32 * 324; idx += 256) {
            const int ci = idx / 324;
            const int r = idx - ci * 324;
            const int iy = r / 18;
            const int ix = r - iy * 18;
            const int sy = y0 + iy, sx = x0 + ix;
            float v = 0.f;
            if ((unsigned)sy < 256u && (unsigned)sx < 256u)
                v = b2f(h1[(((size_t)b * 128 + cc + ci) << 16) + (sy << 8) + sx]);
            lds[idx] = v;
        }
        __syncthreads();

        for (int ci = 0; ci < 32; ++ci) {
            float vin[9];
            const float* lp = &lds[ci * 324 + py * 18 + px];
#pragma unroll
            for (int kh = 0; kh < 3; ++kh)
#pragma unroll
                for (int kw = 0; kw < 3; ++kw) vin[kh * 3 + kw] = lp[kh * 18 + kw];
            const float* wp = w2eff + (((size_t)b * 128 + (cc + ci)) * 9) * 128 + ocb;
#pragma unroll
            for (int t = 0; t < 9; ++t) {
#pragma unroll
                for (int oc = 0; oc < 16; ++oc)
                    acc[oc] = fmaf(vin[t], wp[t * 128 + oc], acc[oc]);
            }
        }
        __syncthreads();
    }

    // 1x1 learned shortcut on raw x
    if (isbf) {
        const bf16* xp = (const bf16*)x;
        for (int i = 0; i < 64; ++i) {
            const float xv = b2f(xp[(((size_t)b * 64 + i) << 16) + (gy << 8) + gx]);
            const float* wp = scwf + i * 128 + ocb;
#pragma unroll
            for (int oc = 0; oc < 16; ++oc) acc[oc] = fmaf(xv, wp[oc], acc[oc]);
        }
    } else {
        const float* xp = (const float*)x;
        for (int i = 0; i < 64; ++i) {
            const float xv = xp[(((size_t)b * 64 + i) << 16) + (gy << 8) + gx];
            const float* wp = scwf + i * 128 + ocb;
#pragma unroll
            for (int oc = 0; oc < 16; ++oc) acc[oc] = fmaf(xv, wp[oc], acc[oc]);
        }
    }

    const float nw = ldin(noise_w, 0, isbf);
    const float nv = nw * ldin(noise, ((size_t)b << 16) + (gy << 8) + gx, isbf);
    const float k = 0.70710678118654752f;
    if (isbf) {
        bf16* op = (bf16*)out;
#pragma unroll
        for (int oc = 0; oc < 16; ++oc)
            op[(((size_t)b * 128 + ocb + oc) << 16) + (gy << 8) + gx] =
                __float2bfloat16((acc[oc] + nv) * k);
    } else {
        float* op = (float*)out;
#pragma unroll
        for (int oc = 0; oc < 16; ++oc)
            op[(((size_t)b * 128 + ocb + oc) << 16) + (gy << 8) + gx] = (acc[oc] + nv) * k;
    }
}

extern "C" void kernel_launch(void* const* d_in, const int* in_sizes, int n_in,
                              void* d_out, int out_size, void* d_ws, size_t ws_size,
                              hipStream_t stream) {
    const void* x     = d_in[0];
    const void* s     = d_in[1];
    const void* noise = d_in[2];
    const void* a1w   = d_in[3];
    const void* a1b   = d_in[4];
    const void* w1    = d_in[5];
    const void* a2w   = d_in[6];
    const void* a2b   = d_in[7];
    const void* w2    = d_in[8];
    const void* nw    = d_in[9];
    const void* scw   = d_in[10];

    char* ws = (char*)d_ws;
    // ws layout (bytes):
    //   flag  int                    @0        (256-byte slot)
    //   w1eff fp32 [8][64][9][128]   @256        2,359,296
    //   w2eff fp32 [8][128][9][128]  @+          4,718,592
    //   scwf  fp32 [64][128]         @+             32,768
    //   h1    bf16 [8][128][256][256]@+        134,217,728   (~141.3 MB total)
    int*   flag  = (int*)ws;
    float* w1eff = (float*)(ws + 256);
    float* w2eff = (float*)(ws + 256 + 2359296);
    float* scwf  = (float*)(ws + 256 + 2359296 + 4718592);
    bf16*  h1    = (bf16*) (ws + 256 + 2359296 + 4718592 + 32768);

    probe_kernel<<<dim3(1), dim3(256), 0, stream>>>(x, flag);
    weights_kernel<<<dim3(8), dim3(256), 0, stream>>>(s, a1w, a1b, w1, a2w, a2b, w2,
                                                      scw, w1eff, w2eff, scwf, flag);
    dim3 grid(16, 16, 64);
    conv1_kernel<<<grid, dim3(256), 0, stream>>>(x, noise, nw, w1eff, h1, flag);
    conv2_kernel<<<grid, dim3(256), 0, stream>>>(h1, x, noise, nw, w2eff, scwf, d_out, flag);
}